// Round 9
// baseline (417.575 us; speedup 1.0000x reference)
//
#include <hip/hip_runtime.h>

// Swin shifted-window attention, MI355X gfx950.  R8: A-in-registers GEMMs,
// 2 independent blocks/CU (256 thr, 4 waves, BM=128), 2-deep B prefetch.
// k_qkv: 512 blocks; A panel (128 tok) gathered from x once into af[2][16] regs;
//        B (wqkv) streamed via 8KB LDS dbuf; 12 bn-tiles/block.
// k_attn: per-window attention (unchanged).
// k_out: same structure as k_qkv, A=ao, 4 bn-tiles, NT stores on final out only.
// d_out holds q|k f16 overlay until k_out overwrites it (fp32).
// ws: [0,64MiB) ao; [64,128MiB) vt.

using f16   = _Float16;
using f16x8 = __attribute__((ext_vector_type(8))) _Float16;
using f16x4 = __attribute__((ext_vector_type(4))) _Float16;
using f32x4 = __attribute__((ext_vector_type(4))) float;

#define MFMA16(a, b, c) __builtin_amdgcn_mfma_f32_16x16x32_f16((a), (b), (c), 0, 0, 0)
#define SCHEDBAR() __builtin_amdgcn_sched_barrier(0)
#define VMCNT4() asm volatile("s_waitcnt vmcnt(4)" ::: "memory")
#define VMCNT0() asm volatile("s_waitcnt vmcnt(0)" ::: "memory")
#define LGKM0()  asm volatile("s_waitcnt lgkmcnt(0)" ::: "memory")
#define BAR()    __builtin_amdgcn_s_barrier()

static constexpr int QK_HALF = 65536 * 512;

__device__ __forceinline__ void nts4f(f32x4 v, float* p) {
  __builtin_nontemporal_store(v, (f32x4*)p);
}

__device__ __forceinline__ int tok2patch(int t) {
  int b = t >> 12, rem = t & 4095;
  int widx = rem >> 6, s = rem & 63;
  int pr = (((widx >> 3) << 3) + (s >> 3) + 4) & 63;
  int pc = (((widx & 7) << 3) + (s & 7) + 4) & 63;
  return ((b << 12) | (pr << 6) | pc) << 9;
}

__device__ __forceinline__ f16x8 cvt8(float4 a, float4 b) {
  f16x8 h = { (f16)a.x, (f16)a.y, (f16)a.z, (f16)a.w,
              (f16)b.x, (f16)b.y, (f16)b.z, (f16)b.w };
  return h;
}

// ---------------------------------------------------------------------------
// Kernel 1: QKV projection, A-in-registers, BM=128, 4 waves.
// Per K-step u: [8 bf ds_read] [16 MFMA] [vmcnt(4): pair(u+1) ready]
//               [WRITEB pair(u+1)] [LOADB pair(u+3)] [lgkm0; BAR]
// Pairs alternate reg sets by parity (static indexing).
// ---------------------------------------------------------------------------
__global__ __launch_bounds__(256, 2) void k_qkv(const float* __restrict__ x,
                                                const float* __restrict__ wq,
                                                const float* __restrict__ bq,
                                                f16* __restrict__ qk,
                                                f16* __restrict__ vt) {
  __shared__ __align__(16) char smem[37376];  // B0|B1 8KB + 4 x 5120B Cw
  f16* const B0 = (f16*)smem;
  f16* const B1 = (f16*)(smem + 8192);

  const int tid = threadIdx.x;
  const int lane = tid & 63, wave = tid >> 6;
  const int jlo = lane & 15, g = lane >> 4;
  const int bm = blockIdx.x;  // 512 blocks (no cross-block A reuse -> no swizzle)

  const int nl = tid >> 1, kh = (tid & 1) * 16;   // B staging: row, k-half
  const int bsw = (nl >> 1) & 3, bc0 = (tid & 1) * 2;

  // ---- A panel -> registers (gather + cvt), af[mt][ks] ----
  const int r0 = tok2patch(bm * 128 + wave * 32 + jlo);
  const int r1 = tok2patch(bm * 128 + wave * 32 + 16 + jlo);
  f16x8 af[2][16];
#pragma unroll
  for (int kg = 0; kg < 4; ++kg) {
    float4 t0[4][2], t1[4][2];
#pragma unroll
    for (int k4 = 0; k4 < 4; ++k4) {
      const int ko = (kg * 4 + k4) * 32 + g * 8;
      t0[k4][0] = *(const float4*)(x + r0 + ko);
      t0[k4][1] = *(const float4*)(x + r0 + ko + 4);
      t1[k4][0] = *(const float4*)(x + r1 + ko);
      t1[k4][1] = *(const float4*)(x + r1 + ko + 4);
    }
#pragma unroll
    for (int k4 = 0; k4 < 4; ++k4) {
      af[0][kg * 4 + k4] = cvt8(t0[k4][0], t0[k4][1]);
      af[1][kg * 4 + k4] = cvt8(t1[k4][0], t1[k4][1]);
    }
    SCHEDBAR();
  }

  f32x4 acc[2][8] = {};
  float4 rbA[4], rbB[4];
#define LOADB(U2, RB)                                                     \
  do {                                                                    \
    const int bn2_ = (U2) >> 4, k2_ = ((U2) & 15) * 32;                   \
    const float* bs_ = wq + (bn2_ * 128 + nl) * 512 + k2_ + kh;           \
    RB[0] = *(const float4*)(bs_);     RB[1] = *(const float4*)(bs_ + 4); \
    RB[2] = *(const float4*)(bs_ + 8); RB[3] = *(const float4*)(bs_ + 12);\
  } while (0)
#define WRITEB(Bp, RB)                                                       \
  do {                                                                       \
    *(f16x8*)((Bp) + nl * 32 + ((bc0 ^ bsw) * 8))       = cvt8(RB[0], RB[1]);\
    *(f16x8*)((Bp) + nl * 32 + (((bc0 + 1) ^ bsw) * 8)) = cvt8(RB[2], RB[3]);\
  } while (0)

  // prologue: commit pair0, put pair1->rbB, pair2->rbA in flight
  LOADB(0, rbA);
  SCHEDBAR();
  VMCNT0();
  WRITEB(B0, rbA);
  LOADB(1, rbB);
  LOADB(2, rbA);
  LGKM0();
  BAR();

#pragma unroll 1
  for (int bn = 0; bn < 12; ++bn) {
    f16* const Cw = (f16*)(smem + 16384) + wave * 2560;  // 5120 B/wave
#pragma unroll
    for (int ks = 0; ks < 16; ++ks) {
      const int u = bn * 16 + ks;
      f16* const Bc = (u & 1) ? B1 : B0;
      f16* const Bn = (u & 1) ? B0 : B1;
      f16x8 bf[8];
#pragma unroll
      for (int nt = 0; nt < 8; ++nt) {
        const int n = nt * 16 + jlo;
        bf[nt] = *(const f16x8*)(Bc + n * 32 + ((g ^ ((n >> 1) & 3)) * 8));
      }
      __builtin_amdgcn_s_setprio(1);
#pragma unroll
      for (int mt = 0; mt < 2; ++mt)
#pragma unroll
        for (int nt = 0; nt < 8; ++nt)
          acc[mt][nt] = MFMA16(af[mt][ks], bf[nt], acc[mt][nt]);
      __builtin_amdgcn_s_setprio(0);
      if (u + 1 < 192) {
        if (u < 190) { VMCNT4(); } else { VMCNT0(); }
        if ((ks & 1) == 0) {  // pair(u+1) parity: (u+1)&1 == 1 -> rbB
          WRITEB(Bn, rbB);
          SCHEDBAR();
          if (u + 3 < 192) LOADB(u + 3, rbB);
        } else {
          WRITEB(Bn, rbA);
          SCHEDBAR();
          if (u + 3 < 192) LOADB(u + 3, rbA);
        }
      }
      LGKM0();
      BAR();
    }
    // ---- epilogue tile (bm, bn): per-wave Cw, 2 column-half passes ----
    float bias[8];
#pragma unroll
    for (int nt = 0; nt < 8; ++nt) bias[nt] = bq[bn * 128 + nt * 16 + jlo];
    if (bn < 8) {  // q or k: token rows, 2 x 64-col halves (Cw 32x72 f16)
      f16* const gb = (bn < 4) ? (qk + bn * 128) : (qk + QK_HALF + (bn - 4) * 128);
#pragma unroll
      for (int hf = 0; hf < 2; ++hf) {
#pragma unroll
        for (int n2 = 0; n2 < 4; ++n2) {
          const int nt = hf * 4 + n2;
#pragma unroll
          for (int mt = 0; mt < 2; ++mt)
#pragma unroll
            for (int r = 0; r < 4; ++r)
              Cw[(mt * 16 + g * 4 + r) * 72 + n2 * 16 + jlo] =
                  (f16)(acc[mt][nt][r] + bias[nt]);
        }
        LGKM0();
#pragma unroll
        for (int p = 0; p < 4; ++p) {  // 8 lanes/row -> 128B contiguous
          const int lr = p * 8 + (lane >> 3);
          const int ch = lane & 7;
          const int trow = bm * 128 + wave * 32 + lr;
          *(f16x8*)(gb + trow * 512 + hf * 64 + ch * 8) =
              *(const f16x8*)(Cw + lr * 72 + ch * 8);
        }
        LGKM0();
      }
    } else {  // v: transpose to vt[w][h][d][s], 2 x 64-col halves (Cw 64x40 f16)
      const int w = bm * 2 + (wave >> 1);
      const int s0 = (wave & 1) * 32;
#pragma unroll
      for (int hf = 0; hf < 2; ++hf) {
#pragma unroll
        for (int n2 = 0; n2 < 4; ++n2) {
          const int nt = hf * 4 + n2;
#pragma unroll
          for (int mt = 0; mt < 2; ++mt) {
            f16x4 pk = { (f16)(acc[mt][nt][0] + bias[nt]), (f16)(acc[mt][nt][1] + bias[nt]),
                         (f16)(acc[mt][nt][2] + bias[nt]), (f16)(acc[mt][nt][3] + bias[nt]) };
            *(f16x4*)(Cw + (n2 * 16 + jlo) * 40 + mt * 16 + g * 4) = pk;
          }
        }
        LGKM0();
#pragma unroll
        for (int p = 0; p < 4; ++p) {  // 4 lanes/col -> 64B contiguous
          const int cl = p * 16 + (lane >> 2);
          const int ch = lane & 3;
          const int n = (bn - 8) * 128 + hf * 64 + cl;
          const int h = n >> 5, d = n & 31;
          *(f16x8*)(vt + ((w * 16 + h) * 32 + d) * 64 + s0 + ch * 8) =
              *(const f16x8*)(Cw + cl * 40 + ch * 8);
        }
        LGKM0();
      }
    }
#pragma unroll
    for (int mt = 0; mt < 2; ++mt)
#pragma unroll
      for (int nt = 0; nt < 8; ++nt)
        acc[mt][nt] = (f32x4){0.f, 0.f, 0.f, 0.f};
  }
#undef LOADB
#undef WRITEB
}

// ---------------------------------------------------------------------------
// Kernel 2: per-window attention (verified, unchanged).
// ---------------------------------------------------------------------------
__global__ __launch_bounds__(256) void k_attn(const f16* __restrict__ qk,
                                              const f16* __restrict__ vt,
                                              f16* __restrict__ ao) {
  __shared__ f16 P[4][64 * 72];
  const int w = blockIdx.x;
  const int widx = w & 63;
  const bool er = (widx >> 3) == 7;
  const bool ec = (widx & 7) == 7;
  const int tid = threadIdx.x;
  const int lane = tid & 63, wave = tid >> 6;
  const int jlo = lane & 15, g = lane >> 4;
  const int tb = w * 64;
  f16* Pw = P[wave];
  const float scale = 0.17677669529663687f;

#pragma unroll 1
  for (int hh = 0; hh < 4; ++hh) {
    const int h = wave * 4 + hh;
    f16x8 qa[4], kb[4];
#pragma unroll
    for (int mt = 0; mt < 4; ++mt)
      qa[mt] = *(const f16x8*)(qk + (tb + mt * 16 + jlo) * 512 + h * 32 + g * 8);
#pragma unroll
    for (int nt = 0; nt < 4; ++nt)
      kb[nt] = *(const f16x8*)(qk + QK_HALF + (tb + nt * 16 + jlo) * 512 + h * 32 + g * 8);
    f32x4 sc[4][4] = {};
#pragma unroll
    for (int mt = 0; mt < 4; ++mt)
#pragma unroll
      for (int nt = 0; nt < 4; ++nt)
        sc[mt][nt] = MFMA16(qa[mt], kb[nt], sc[mt][nt]);

    int gj[4];
#pragma unroll
    for (int nt = 0; nt < 4; ++nt) {
      int j = nt * 16 + jlo;
      gj[nt] = ((er && ((j >> 3) >= 4)) ? 2 : 0) | ((ec && ((j & 7) >= 4)) ? 1 : 0);
    }
    float rinv[4][4];
#pragma unroll
    for (int mt = 0; mt < 4; ++mt) {
#pragma unroll
      for (int r = 0; r < 4; ++r) {
        const int i = mt * 16 + g * 4 + r;
        const int gi = ((er && ((i >> 3) >= 4)) ? 2 : 0) | ((ec && ((i & 7) >= 4)) ? 1 : 0);
        float v0 = (gi == gj[0]) ? sc[mt][0][r] * scale : -1e9f;
        float v1 = (gi == gj[1]) ? sc[mt][1][r] * scale : -1e9f;
        float v2 = (gi == gj[2]) ? sc[mt][2][r] * scale : -1e9f;
        float v3 = (gi == gj[3]) ? sc[mt][3][r] * scale : -1e9f;
        float m = fmaxf(fmaxf(v0, v1), fmaxf(v2, v3));
        m = fmaxf(m, __shfl_xor(m, 1));
        m = fmaxf(m, __shfl_xor(m, 2));
        m = fmaxf(m, __shfl_xor(m, 4));
        m = fmaxf(m, __shfl_xor(m, 8));
        float p0 = __expf(v0 - m), p1 = __expf(v1 - m);
        float p2 = __expf(v2 - m), p3 = __expf(v3 - m);
        float s = p0 + p1 + p2 + p3;
        s += __shfl_xor(s, 1);
        s += __shfl_xor(s, 2);
        s += __shfl_xor(s, 4);
        s += __shfl_xor(s, 8);
        rinv[mt][r] = 1.0f / s;
        sc[mt][0][r] = p0; sc[mt][1][r] = p1; sc[mt][2][r] = p2; sc[mt][3][r] = p3;
      }
    }
#pragma unroll
    for (int mt = 0; mt < 4; ++mt)
#pragma unroll
      for (int nt = 0; nt < 4; ++nt)
#pragma unroll
        for (int r = 0; r < 4; ++r)
          Pw[(mt * 16 + g * 4 + r) * 72 + nt * 16 + jlo] = (f16)sc[mt][nt][r];
    asm volatile("s_waitcnt lgkmcnt(0)" ::: "memory");

    f32x4 o[4][2] = {};
#pragma unroll
    for (int ks = 0; ks < 2; ++ks) {
      f16x8 pa[4], vb[2];
#pragma unroll
      for (int mt = 0; mt < 4; ++mt)
        pa[mt] = *(const f16x8*)((const char*)Pw + (mt * 16 + jlo) * 144 + ks * 64 + g * 16);
#pragma unroll
      for (int nt = 0; nt < 2; ++nt)
        vb[nt] = *(const f16x8*)(vt + ((w * 16 + h) * 32 + nt * 16 + jlo) * 64 + ks * 32 + g * 8);
#pragma unroll
      for (int mt = 0; mt < 4; ++mt)
#pragma unroll
        for (int nt = 0; nt < 2; ++nt)
          o[mt][nt] = MFMA16(pa[mt], vb[nt], o[mt][nt]);
    }
#pragma unroll
    for (int mt = 0; mt < 4; ++mt)
#pragma unroll
      for (int nt = 0; nt < 2; ++nt)
#pragma unroll
        for (int r = 0; r < 4; ++r)
          Pw[(mt * 16 + g * 4 + r) * 40 + nt * 16 + jlo] =
              (f16)(o[mt][nt][r] * rinv[mt][r]);
    f16* arow = ao + (tb + lane) * 512 + h * 32;
#pragma unroll
    for (int c = 0; c < 4; ++c)
      *(f16x8*)(arow + c * 8) = *(const f16x8*)(Pw + lane * 40 + c * 8);
  }
}

// ---------------------------------------------------------------------------
// Kernel 3: output projection, A(ao)-in-registers, BM=128, 4 waves,
// scatter via tok2patch (NT).  512 blocks x 4 bn-tiles.
// ---------------------------------------------------------------------------
__global__ __launch_bounds__(256, 2) void k_out(const f16* __restrict__ ao,
                                                const float* __restrict__ wo,
                                                const float* __restrict__ bo,
                                                float* __restrict__ out) {
  __shared__ __align__(16) char smem[51200];  // B0|B1 8KB + 4 x 8704B Cw(f32)
  f16* const B0 = (f16*)smem;
  f16* const B1 = (f16*)(smem + 8192);

  const int tid = threadIdx.x;
  const int lane = tid & 63, wave = tid >> 6;
  const int jlo = lane & 15, g = lane >> 4;
  const int bm = blockIdx.x;  // 512 blocks

  const int nl = tid >> 1, kh = (tid & 1) * 16;
  const int bsw = (nl >> 1) & 3, bc0 = (tid & 1) * 2;

  const f16* const a0 = ao + (bm * 128 + wave * 32 + jlo) * 512 + g * 8;
  const f16* const a1 = a0 + 16 * 512;
  f16x8 af[2][16];
#pragma unroll
  for (int ks = 0; ks < 16; ++ks) {
    af[0][ks] = *(const f16x8*)(a0 + ks * 32);
    af[1][ks] = *(const f16x8*)(a1 + ks * 32);
  }

  f32x4 acc[2][8] = {};
  float4 rbA[4], rbB[4];
#define LOADB(U2, RB)                                                     \
  do {                                                                    \
    const int bn2_ = (U2) >> 4, k2_ = ((U2) & 15) * 32;                   \
    const float* bs_ = wo + (bn2_ * 128 + nl) * 512 + k2_ + kh;           \
    RB[0] = *(const float4*)(bs_);     RB[1] = *(const float4*)(bs_ + 4); \
    RB[2] = *(const float4*)(bs_ + 8); RB[3] = *(const float4*)(bs_ + 12);\
  } while (0)
#define WRITEB(Bp, RB)                                                       \
  do {                                                                       \
    *(f16x8*)((Bp) + nl * 32 + ((bc0 ^ bsw) * 8))       = cvt8(RB[0], RB[1]);\
    *(f16x8*)((Bp) + nl * 32 + (((bc0 + 1) ^ bsw) * 8)) = cvt8(RB[2], RB[3]);\
  } while (0)

  LOADB(0, rbA);
  SCHEDBAR();
  VMCNT0();
  WRITEB(B0, rbA);
  LOADB(1, rbB);
  LOADB(2, rbA);
  LGKM0();
  BAR();

#pragma unroll 1
  for (int bn = 0; bn < 4; ++bn) {
    float* const Cw = (float*)((char*)smem + 16384) + wave * 2176;  // 8704 B/wave
#pragma unroll
    for (int ks = 0; ks < 16; ++ks) {
      const int u = bn * 16 + ks;
      f16* const Bc = (u & 1) ? B1 : B0;
      f16* const Bn = (u & 1) ? B0 : B1;
      f16x8 bf[8];
#pragma unroll
      for (int nt = 0; nt < 8; ++nt) {
        const int n = nt * 16 + jlo;
        bf[nt] = *(const f16x8*)(Bc + n * 32 + ((g ^ ((n >> 1) & 3)) * 8));
      }
      __builtin_amdgcn_s_setprio(1);
#pragma unroll
      for (int mt = 0; mt < 2; ++mt)
#pragma unroll
        for (int nt = 0; nt < 8; ++nt)
          acc[mt][nt] = MFMA16(af[mt][ks], bf[nt], acc[mt][nt]);
      __builtin_amdgcn_s_setprio(0);
      if (u + 1 < 64) {
        if (u < 62) { VMCNT4(); } else { VMCNT0(); }
        if ((ks & 1) == 0) {
          WRITEB(Bn, rbB);
          SCHEDBAR();
          if (u + 3 < 64) LOADB(u + 3, rbB);
        } else {
          WRITEB(Bn, rbA);
          SCHEDBAR();
          if (u + 3 < 64) LOADB(u + 3, rbA);
        }
      }
      LGKM0();
      BAR();
    }
    // epilogue: 2 x 64-col halves, fp32 rows scattered via tok2patch (NT)
#pragma unroll
    for (int hf = 0; hf < 2; ++hf) {
#pragma unroll
      for (int n2 = 0; n2 < 4; ++n2) {
        const int nt = hf * 4 + n2;
        const float bias = bo[bn * 128 + nt * 16 + jlo];
#pragma unroll
        for (int mt = 0; mt < 2; ++mt)
#pragma unroll
          for (int r = 0; r < 4; ++r)
            Cw[(mt * 16 + g * 4 + r) * 68 + n2 * 16 + jlo] = acc[mt][nt][r] + bias;
      }
      LGKM0();
#pragma unroll
      for (int p = 0; p < 8; ++p) {  // 16 lanes/row -> 256B contiguous
        const int lr = (p >> 1) * 8 + (lane >> 3);
        const int ch = (p & 1) * 8 + (lane & 7);
        const int trow = bm * 128 + wave * 32 + lr;
        nts4f(*(const f32x4*)(Cw + lr * 68 + ch * 4),
              out + tok2patch(trow) + bn * 128 + hf * 64 + ch * 4);
      }
      LGKM0();
    }
#pragma unroll
    for (int mt = 0; mt < 2; ++mt)
#pragma unroll
      for (int nt = 0; nt < 8; ++nt)
        acc[mt][nt] = (f32x4){0.f, 0.f, 0.f, 0.f};
  }
#undef LOADB
#undef WRITEB
}

extern "C" void kernel_launch(void* const* d_in, const int* in_sizes, int n_in,
                              void* d_out, int out_size, void* d_ws, size_t ws_size,
                              hipStream_t stream) {
  const float* x  = (const float*)d_in[0];
  const float* wq = (const float*)d_in[1];
  const float* bq = (const float*)d_in[2];
  const float* wo = (const float*)d_in[3];
  const float* bo = (const float*)d_in[4];
  float* out = (float*)d_out;

  f16* qk = (f16*)d_out;                        // q|k overlay (128 MiB)
  f16* ao = (f16*)d_ws;                         // attention output (64 MiB)
  f16* vt = (f16*)((char*)d_ws + (64u << 20));  // V transposed (64 MiB)

  k_qkv<<<dim3(512), 256, 0, stream>>>(x, wq, bq, qk, vt);
  k_attn<<<dim3(1024), 256, 0, stream>>>(qk, vt, ao);
  k_out<<<dim3(512), 256, 0, stream>>>(ao, wo, bo, out);
}